// Round 9
// baseline (143.625 us; speedup 1.0000x reference)
//
#include <hip/hip_runtime.h>
#include <hip/hip_bf16.h>

#define T_ 8
#define H_ 96
#define W_ 160
#define C_ 256
#define F_ 256
#define M_ (T_ * H_ * W_)   // 122880

typedef __bf16 bf16_t;
typedef __bf16 bf16x4 __attribute__((ext_vector_type(4)));
typedef __bf16 bf16x8 __attribute__((ext_vector_type(8)));
typedef float  f32x4  __attribute__((ext_vector_type(4)));

// ---------------- pass 0: WpT[f][c] = bf16(Wp[c][f]) ----------------
__global__ void wp_transpose_kernel(const float* __restrict__ Wp,
                                    bf16_t* __restrict__ WpT) {
    int f = blockIdx.x;   // 0..255
    int c = threadIdx.x;  // 0..255
    WpT[f * C_ + c] = (bf16_t)Wp[c * F_ + f];
}

// ---------------- pass 1: depthwise 3x3x3 via LDS slab ----------------
// r3..r8 lesson: the HBM-direct register-stencil structure is pinned at
// ~94 global loads/thread x ~42cy serialization (~98us) and the scheduler
// defeats every source-level batching attempt. This kernel collapses the
// global-instruction count instead: stage an [8t][10h][12w][16c] f32 slab
// (61.4KB, w padded 10->12 so ds_read banks = 4cq+16((w+h)&1): uniform,
// conflict-free) with ~13 f32x4 loads/thread, then compute the whole
// 8x8x8x16 output tile from LDS (72 ds_read_b128 + 216 pk-fma per thread).
#define HP 10
#define WPAD 12
#define XIDX(t, h, w) ((((t) * HP + (h)) * WPAD + (w)) * 16)

__global__ __launch_bounds__(256, 2) void dw_conv_kernel(const float* __restrict__ x,
                                                         const float* __restrict__ Wd,
                                                         bf16_t* __restrict__ dw) {
    __shared__ float xs[T_ * HP * WPAD * 16];   // 61440 B
    __shared__ float Wsw[27 * 16];              //  1728 B

    // XCD-chunked swizzle: grid 3840 % 8 == 0 -> bijective
    int nchunk = gridDim.x >> 3;
    int bb  = (blockIdx.x & 7) * nchunk + (blockIdx.x >> 3);
    // adjacent bb -> adjacent spatial tiles (same c-group) for halo L2 reuse
    int sp  = bb % 240;            // 12 h-tiles * 20 w-tiles
    int cg  = bb / 240;            // 0..15
    int wt  = sp % 20, ht = sp / 20;
    int c0  = cg * 16, h0 = ht * 8, w0 = wt * 8;

    int tid = threadIdx.x;

    // ---- stage weights: 27 taps x 16 ch (108 f32x4) ----
    if (tid < 108) {
        int k = tid >> 2, q = tid & 3;
        *(f32x4*)&Wsw[k * 16 + q * 4] = *(const f32x4*)&Wd[k * C_ + c0 + q * 4];
    }
    // ---- stage x slab: 8t x 10h x 10w x 4 c-quads = 3200 f32x4 ----
    for (int i = tid; i < 3200; i += 256) {
        int q  = i >> 2, cq = i & 3;
        int w  = q % 10, h = (q / 10) % 10, t = q / 100;
        int hg = h0 + h - 1, wg = w0 + w - 1;
        f32x4 v = {};
        if ((unsigned)hg < (unsigned)H_ && (unsigned)wg < (unsigned)W_)
            v = *(const f32x4*)&x[(((t * H_) + hg) * W_ + wg) * C_ + c0 + cq * 4];
        *(f32x4*)&xs[XIDX(t, h, w) + cq * 4] = v;
    }
    __syncthreads();

    // ---- compute: thread = (h', w', cq), all 8 t outputs ----
    int cq = tid & 3;
    int w_ = (tid >> 2) & 7;
    int h_ = tid >> 5;

    // weights resident (27 f32x4); worst case compiler re-reads from LDS
    f32x4 wv[27];
#pragma unroll
    for (int k = 0; k < 27; ++k) wv[k] = *(const f32x4*)&Wsw[k * 16 + cq * 4];

    f32x4 acc[8] = {};

#pragma unroll
    for (int ti = 0; ti < 8; ++ti) {
        // 9 neighborhood reads for this t-plane
        f32x4 xv[3][3];
#pragma unroll
        for (int kh = 0; kh < 3; ++kh)
#pragma unroll
            for (int kw = 0; kw < 3; ++kw)
                xv[kh][kw] = *(const f32x4*)&xs[XIDX(ti, h_ + kh, w_ + kw) + cq * 4];
        // consume into up to 3 t-outputs: t_out = ti + 1 - kt
#pragma unroll
        for (int kt = 0; kt < 3; ++kt) {
            int to = ti + 1 - kt;
            if (to < 0 || to >= 8) continue;   // compile-time
#pragma unroll
            for (int kh = 0; kh < 3; ++kh)
#pragma unroll
                for (int kw = 0; kw < 3; ++kw)
                    acc[to] += xv[kh][kw] * wv[(kt * 3 + kh) * 3 + kw];
        }
    }

    // ---- write bf16 output ----
#pragma unroll
    for (int t = 0; t < 8; ++t) {
        bf16x4 o;
#pragma unroll
        for (int q = 0; q < 4; ++q) o[q] = (bf16_t)acc[t][q];
        *(bf16x4*)&dw[((t * H_ + h0 + h_) * W_ + w0 + w_) * C_ + c0 + cq * 4] = o;
    }
}

// ---------------- pass 2: GEMM [M,256]x[256,256] bf16 MFMA + ReLU ----------------
#define BM 128
#define BN 128
#define BK 32
#define LDSTR 40  // 32 + 8 pad: fragment ds_read_b128 2-way (free) instead of 8-way

__global__ __launch_bounds__(256) void gemm_kernel(const bf16_t* __restrict__ A,   // dw  [M][C]
                                                   const bf16_t* __restrict__ Bt,  // WpT [F][C] (n-major)
                                                   float* __restrict__ out) {      // [M][F]
    __shared__ __align__(16) bf16_t As[BM * LDSTR];
    __shared__ __align__(16) bf16_t Bs[BN * LDSTR];

    int m0   = blockIdx.x * BM;
    int n0   = blockIdx.y * BN;
    int tid  = threadIdx.x;
    int lane = tid & 63;
    int wid  = tid >> 6;
    int wr   = wid >> 1;   // 0..1
    int wc   = wid & 1;    // 0..1
    int r16  = lane & 15;
    int kg   = lane >> 4;  // 0..3

    f32x4 acc[4][4] = {};

    for (int k0 = 0; k0 < C_; k0 += BK) {
        __syncthreads();
#pragma unroll
        for (int it = 0; it < 2; ++it) {
            int slot = tid + it * 256;       // 0..511
            int row  = slot >> 2;            // 0..127
            int seg  = slot & 3;             // 0..3 (8 bf16 each)
            uint4 va = *(const uint4*)&A[(long)(m0 + row) * C_ + k0 + seg * 8];
            *(uint4*)&As[row * LDSTR + seg * 8] = va;
            uint4 vb = *(const uint4*)&Bt[(n0 + row) * C_ + k0 + seg * 8];
            *(uint4*)&Bs[row * LDSTR + seg * 8] = vb;
        }
        __syncthreads();

        bf16x8 af[4], bfr[4];
#pragma unroll
        for (int m = 0; m < 4; ++m)
            af[m] = *(const bf16x8*)&As[(wr * 64 + m * 16 + r16) * LDSTR + kg * 8];
#pragma unroll
        for (int n = 0; n < 4; ++n)
            bfr[n] = *(const bf16x8*)&Bs[(wc * 64 + n * 16 + r16) * LDSTR + kg * 8];

#pragma unroll
        for (int m = 0; m < 4; ++m)
#pragma unroll
            for (int n = 0; n < 4; ++n)
                acc[m][n] = __builtin_amdgcn_mfma_f32_16x16x32_bf16(af[m], bfr[n], acc[m][n], 0, 0, 0);
    }

    // epilogue: ReLU + fp32 store.  D layout: row=(l>>4)*4+r, col=l&15
    int rbase = m0 + wr * 64 + kg * 4;
    int cbase = n0 + wc * 64 + r16;
#pragma unroll
    for (int m = 0; m < 4; ++m)
#pragma unroll
        for (int n = 0; n < 4; ++n)
#pragma unroll
            for (int r = 0; r < 4; ++r) {
                float v = acc[m][n][r];
                v = v > 0.f ? v : 0.f;
                out[(long)(rbase + m * 16 + r) * F_ + cbase + n * 16] = v;
            }
}

extern "C" void kernel_launch(void* const* d_in, const int* in_sizes, int n_in,
                              void* d_out, int out_size, void* d_ws, size_t ws_size,
                              hipStream_t stream) {
    const float* x  = (const float*)d_in[0];
    const float* Wd = (const float*)d_in[1];
    const float* Wp = (const float*)d_in[2];
    float* out = (float*)d_out;

    bf16_t* dw  = (bf16_t*)d_ws;                                  // M_*C_ bf16 = 62,914,560 B
    bf16_t* WpT = (bf16_t*)((char*)d_ws + (size_t)M_ * C_ * 2);   // + 131,072 B

    wp_transpose_kernel<<<F_, C_, 0, stream>>>(Wp, WpT);
    dw_conv_kernel<<<12 * 20 * 16, 256, 0, stream>>>(x, Wd, dw);
    gemm_kernel<<<dim3(M_ / BM, F_ / BN), 256, 0, stream>>>(dw, WpT, out);
}

// Round 10
// 127.996 us; speedup vs baseline: 1.1221x; 1.1221x over previous
//
#include <hip/hip_runtime.h>
#include <hip/hip_bf16.h>

#define T_ 8
#define H_ 96
#define W_ 160
#define C_ 256
#define F_ 256
#define M_ (T_ * H_ * W_)   // 122880

typedef __bf16 bf16_t;
typedef __bf16 bf16x4 __attribute__((ext_vector_type(4)));
typedef __bf16 bf16x8 __attribute__((ext_vector_type(8)));
typedef float  f32x4  __attribute__((ext_vector_type(4)));

// ---------------- pass 0: WpT[f][c] = bf16(Wp[c][f]) ----------------
// read-coalesced (f contiguous per wave); strided writes are fire-and-forget
__global__ void wp_transpose_kernel(const float* __restrict__ Wp,
                                    bf16_t* __restrict__ WpT) {
    int c = blockIdx.x;   // 0..255
    int f = threadIdx.x;  // 0..255
    WpT[f * C_ + c] = (bf16_t)Wp[c * F_ + f];
}

// ---------------- pass 1: depthwise 3x3x3 conv, fp32 -> bf16 ----------------
// Empirical law from r3..r9: dw time scales with the COUNT of L1-missing
// vmem instructions (~36-40cy each effective); L1-hit loads are ~free.
// r6 = 1.29M wave-instrs @512B -> 98us. This round halves the count with
// f32x4 (1KB/wave-instr): thread = channel-quad, block = h-quad x w-pair,
// grid 1920, 0.65M wave-instrs. Inline consume (no batching arrays -> no
// spill path); weights may be re-read from L1 by the scheduler (proven free
// in r3). launch_bounds(256,2) -> 256-VGPR budget, acc=64 regs fits easily.
__global__ __launch_bounds__(256, 2) void dw_conv_kernel(const float* __restrict__ x,
                                                         const float* __restrict__ Wd,
                                                         bf16_t* __restrict__ dw) {
    // XCD-chunked swizzle: grid 1920 % 8 == 0 -> bijective
    int nchunk = gridDim.x >> 3;
    int bb  = (blockIdx.x & 7) * nchunk + (blockIdx.x >> 3);
    int h4  = bb / (W_ / 2);         // h-quad index, 0..23
    int wq  = bb % (W_ / 2);         // w-pair index, 0..79
    int tid = threadIdx.x;
    int c   = (tid & 63) * 4;        // channel quad: 64 lanes x 4ch = full C
    int wid = tid >> 6;              // wave id
    int hp  = wid & 1;               // h-pair within quad   (wave-uniform)
    int wp  = wid >> 1;              // w within pair        (wave-uniform)
    int h0  = h4 * 4 + hp * 2;
    int w   = wq * 2 + wp;

    // weights: 27 taps x c-quad; compiler may keep resident or re-read (L1-hot)
    f32x4 wreg[27];
#pragma unroll
    for (int k = 0; k < 27; ++k) wreg[k] = *(const f32x4*)&Wd[k * C_ + c];

    f32x4 acc[2][8] = {};
    const int tstride = H_ * W_ * C_;

#pragma unroll
    for (int dh = -1; dh <= 2; ++dh) {
        int hh = h0 + dh;
        if (hh < 0 || hh >= H_) continue;          // wave-uniform
#pragma unroll
        for (int dwi = -1; dwi <= 1; ++dwi) {
            int ww = w + dwi;
            if (ww < 0 || ww >= W_) continue;      // wave-uniform
            int kw = dwi + 1;
            const float* px = x + (hh * W_ + ww) * C_ + c;
#pragma unroll
            for (int tt = 0; tt < 8; ++tt) {
                f32x4 v = *(const f32x4*)&px[tt * tstride];
#pragma unroll
                for (int j = 0; j < 2; ++j) {
                    int kh = dh + 1 - j;
                    if (kh < 0 || kh > 2) continue;   // compile-time
#pragma unroll
                    for (int kt = 0; kt < 3; ++kt) {
                        int to = tt + 1 - kt;
                        if (to < 0 || to >= 8) continue;  // compile-time
                        acc[j][to] += v * wreg[(kt * 3 + kh) * 3 + kw];
                    }
                }
            }
        }
    }

#pragma unroll
    for (int j = 0; j < 2; ++j)
#pragma unroll
        for (int tt = 0; tt < 8; ++tt) {
            bf16x4 o;
#pragma unroll
            for (int q = 0; q < 4; ++q) o[q] = (bf16_t)acc[j][tt][q];
            *(bf16x4*)&dw[((tt * H_ + (h0 + j)) * W_ + w) * C_ + c] = o;
        }
}

// ---------------- pass 2: GEMM [M,256]x[256,256] bf16 MFMA + ReLU ----------------
#define BM 128
#define BN 128
#define BK 32
#define LDSTR 40  // 32 + 8 pad: fragment ds_read_b128 2-way (free) instead of 8-way

__global__ __launch_bounds__(256) void gemm_kernel(const bf16_t* __restrict__ A,   // dw  [M][C]
                                                   const bf16_t* __restrict__ Bt,  // WpT [F][C] (n-major)
                                                   float* __restrict__ out) {      // [M][F]
    __shared__ __align__(16) bf16_t As[BM * LDSTR];
    __shared__ __align__(16) bf16_t Bs[BN * LDSTR];

    int m0   = blockIdx.x * BM;
    int n0   = blockIdx.y * BN;
    int tid  = threadIdx.x;
    int lane = tid & 63;
    int wid  = tid >> 6;
    int wr   = wid >> 1;   // 0..1
    int wc   = wid & 1;    // 0..1
    int r16  = lane & 15;
    int kg   = lane >> 4;  // 0..3

    f32x4 acc[4][4] = {};

    for (int k0 = 0; k0 < C_; k0 += BK) {
        __syncthreads();
#pragma unroll
        for (int it = 0; it < 2; ++it) {
            int slot = tid + it * 256;       // 0..511
            int row  = slot >> 2;            // 0..127
            int seg  = slot & 3;             // 0..3 (8 bf16 each)
            uint4 va = *(const uint4*)&A[(long)(m0 + row) * C_ + k0 + seg * 8];
            *(uint4*)&As[row * LDSTR + seg * 8] = va;
            uint4 vb = *(const uint4*)&Bt[(n0 + row) * C_ + k0 + seg * 8];
            *(uint4*)&Bs[row * LDSTR + seg * 8] = vb;
        }
        __syncthreads();

        bf16x8 af[4], bfr[4];
#pragma unroll
        for (int m = 0; m < 4; ++m)
            af[m] = *(const bf16x8*)&As[(wr * 64 + m * 16 + r16) * LDSTR + kg * 8];
#pragma unroll
        for (int n = 0; n < 4; ++n)
            bfr[n] = *(const bf16x8*)&Bs[(wc * 64 + n * 16 + r16) * LDSTR + kg * 8];

#pragma unroll
        for (int m = 0; m < 4; ++m)
#pragma unroll
            for (int n = 0; n < 4; ++n)
                acc[m][n] = __builtin_amdgcn_mfma_f32_16x16x32_bf16(af[m], bfr[n], acc[m][n], 0, 0, 0);
    }

    // epilogue: ReLU + fp32 store.  D layout: row=(l>>4)*4+r, col=l&15
    int rbase = m0 + wr * 64 + kg * 4;
    int cbase = n0 + wc * 64 + r16;
#pragma unroll
    for (int m = 0; m < 4; ++m)
#pragma unroll
        for (int n = 0; n < 4; ++n)
#pragma unroll
            for (int r = 0; r < 4; ++r) {
                float v = acc[m][n][r];
                v = v > 0.f ? v : 0.f;
                out[(long)(rbase + m * 16 + r) * F_ + cbase + n * 16] = v;
            }
}

extern "C" void kernel_launch(void* const* d_in, const int* in_sizes, int n_in,
                              void* d_out, int out_size, void* d_ws, size_t ws_size,
                              hipStream_t stream) {
    const float* x  = (const float*)d_in[0];
    const float* Wd = (const float*)d_in[1];
    const float* Wp = (const float*)d_in[2];
    float* out = (float*)d_out;

    bf16_t* dw  = (bf16_t*)d_ws;                                  // M_*C_ bf16 = 62,914,560 B
    bf16_t* WpT = (bf16_t*)((char*)d_ws + (size_t)M_ * C_ * 2);   // + 131,072 B

    wp_transpose_kernel<<<C_, F_, 0, stream>>>(Wp, WpT);
    dw_conv_kernel<<<(H_ / 4) * (W_ / 2), 256, 0, stream>>>(x, Wd, dw);
    gemm_kernel<<<dim3(M_ / BM, F_ / BN), 256, 0, stream>>>(dw, WpT, out);
}